// Round 1
// baseline (327.473 us; speedup 1.0000x reference)
//
#include <hip/hip_runtime.h>

// phase split: out[p,b,c,i,j] = x[b,c,2i+p/2,2j+p%2]
// x: [B=64, C=3, H=512, W=512] fp32 -> out: [4, B, C, 256, 256] fp32
// Pure permutation; memory-roofline bound (~402 MB traffic -> ~64 us floor).

__global__ __launch_bounds__(256) void phase_split_kernel(
    const float* __restrict__ x, float* __restrict__ out) {
    constexpr int B = 64, C = 3, H = 512, W = 512;
    constexpr int Hh = H / 2, Wh = W / 2;

    const int lane = threadIdx.x & 63;   // 8-float chunk index within the row
    const int rowi = threadIdx.x >> 6;   // which of the 4 rows this block handles
    const int h = (blockIdx.x << 2) + rowi;  // 0..511
    const int c = blockIdx.y;                // 0..2
    const int b = blockIdx.z;                // 0..63

    const int dy = h & 1;   // vertical phase
    const int i  = h >> 1;  // output row

    // Coalesced read: lane reads 8 consecutive floats (2 x float4 = 32 B).
    const float4* src = reinterpret_cast<const float4*>(
        x + (((size_t)b * C + c) * H + h) * W) + (size_t)lane * 2;
    const float4 a0 = src[0];
    const float4 a1 = src[1];

    // Deinterleave even/odd columns -> two contiguous float4s.
    const float4 ev = make_float4(a0.x, a0.z, a1.x, a1.z); // cols 2j   -> phase 2*dy+0
    const float4 od = make_float4(a0.y, a0.w, a1.y, a1.w); // cols 2j+1 -> phase 2*dy+1

    constexpr size_t plane = (size_t)Hh * Wh;          // 65536
    constexpr size_t phase_stride = (size_t)B * C * plane;

    // out index: ((p*B + b)*C + c)*plane + i*Wh + 4*lane
    float* dst = out + (((size_t)(2 * dy) * B + b) * C + c) * plane
                     + (size_t)i * Wh + (size_t)lane * 4;
    *reinterpret_cast<float4*>(dst) = ev;                  // phase 2*dy
    *reinterpret_cast<float4*>(dst + phase_stride) = od;   // phase 2*dy+1
}

extern "C" void kernel_launch(void* const* d_in, const int* in_sizes, int n_in,
                              void* d_out, int out_size, void* d_ws, size_t ws_size,
                              hipStream_t stream) {
    const float* x = (const float*)d_in[0];
    float* out = (float*)d_out;
    dim3 grid(128, 3, 64);   // h-quads, C, B
    dim3 block(256);
    phase_split_kernel<<<grid, block, 0, stream>>>(x, out);
}